// Round 17
// baseline (396.046 us; speedup 1.0000x reference)
//
#include <hip/hip_runtime.h>
#include <math.h>

#define PLANE 16384   // 128*128
#define NPLANES 512   // B(128) * C(4)

typedef __attribute__((ext_vector_type(2))) unsigned int uint2v;

// ---------------- in-register 2D FWHT-128x128 across a 512-thread block ----------------
// Shuffle-stage pipes: m=1,2 -> DPP quad_perm; m=8 -> DPP row_ror:8; m=16/32 ->
// permlane16/32_swap pair-trick (all VALU). Only m=4 remains on the DS pipe.
__device__ __forceinline__ void fwht2d_reg512(float* __restrict__ v, float* __restrict__ xch,
                                              int W, int L) {
#pragma unroll
    for (int m = 1; m <= 2; m <<= 1) {
#pragma unroll
        for (int r = 0; r < 32; ++r) {
            if (!(r & m)) {
                int s = r | m;
                float a = v[r], b = v[s];
                v[r] = a + b; v[s] = a - b;
            }
        }
    }
    {
        float sg = (L & 1) ? -1.f : 1.f;
#pragma unroll
        for (int r = 0; r < 32; ++r) {
            int xi = __float_as_int(v[r]);
            float p = __int_as_float(__builtin_amdgcn_update_dpp(xi, xi, 0xB1, 0xF, 0xF, false));
            v[r] = fmaf(sg, v[r], p);
        }
    }
    {
        float sg = (L & 2) ? -1.f : 1.f;
#pragma unroll
        for (int r = 0; r < 32; ++r) {
            int xi = __float_as_int(v[r]);
            float p = __int_as_float(__builtin_amdgcn_update_dpp(xi, xi, 0x4E, 0xF, 0xF, false));
            v[r] = fmaf(sg, v[r], p);
        }
    }
    {
        float sg = (L & 4) ? -1.f : 1.f;
#pragma unroll
        for (int r = 0; r < 32; ++r) {
            float p = __shfl_xor(v[r], 4);
            v[r] = fmaf(sg, v[r], p);
        }
    }
    {
        float sg = (L & 8) ? -1.f : 1.f;
#pragma unroll
        for (int r = 0; r < 32; ++r) {
            int xi = __float_as_int(v[r]);
            float p = __int_as_float(__builtin_amdgcn_update_dpp(xi, xi, 0x128, 0xF, 0xF, false));
            v[r] = fmaf(sg, v[r], p);
        }
    }
#pragma unroll
    for (int r = 0; r < 32; r += 2) {
        uint2v s1 = __builtin_amdgcn_permlane16_swap(__float_as_uint(v[r]),
                                                     __float_as_uint(v[r + 1]), false, false);
        float u = __uint_as_float(s1.x) + __uint_as_float(s1.y);
        float w = __uint_as_float(s1.x) - __uint_as_float(s1.y);
        uint2v s2 = __builtin_amdgcn_permlane16_swap(__float_as_uint(u),
                                                     __float_as_uint(w), false, false);
        v[r]     = __uint_as_float(s2.x);
        v[r + 1] = __uint_as_float(s2.y);
    }
#pragma unroll
    for (int r = 0; r < 32; r += 2) {
        uint2v s1 = __builtin_amdgcn_permlane32_swap(__float_as_uint(v[r]),
                                                     __float_as_uint(v[r + 1]), false, false);
        float u = __uint_as_float(s1.x) + __uint_as_float(s1.y);
        float w = __uint_as_float(s1.x) - __uint_as_float(s1.y);
        uint2v s2 = __builtin_amdgcn_permlane32_swap(__float_as_uint(u),
                                                     __float_as_uint(w), false, false);
        v[r]     = __uint_as_float(s2.x);
        v[r + 1] = __uint_as_float(s2.y);
    }
#pragma unroll
    for (int m = 4; m <= 16; m <<= 1) {
#pragma unroll
        for (int r = 0; r < 32; ++r) {
            if (!(r & m)) {
                int s = r | m;
                float a = v[r], b = v[s];
                v[r] = a + b; v[s] = a - b;
            }
        }
    }
#pragma unroll
    for (int mw = 1; mw <= 4; mw <<= 1) {
        int Wp = W ^ mw;
        float sg = (W & mw) ? -1.f : 1.f;
#pragma unroll
        for (int half = 0; half < 2; ++half) {
            __syncthreads();
#pragma unroll
            for (int j = 0; j < 16; ++j)
                xch[(j * 8 + W) * 64 + L] = v[half * 16 + j];
            __syncthreads();
#pragma unroll
            for (int j = 0; j < 16; ++j) {
                float p = xch[(j * 8 + Wp) * 64 + L];
                v[half * 16 + j] = fmaf(sg, v[half * 16 + j], p);
            }
        }
    }
}

template <bool ADDPOST>
__global__ __launch_bounds__(512) void fwht_kernel_t(
    const float* __restrict__ in, const float* __restrict__ vmat,
    const float* __restrict__ tmat, const float* __restrict__ addbuf,
    float* __restrict__ outInv, float* __restrict__ klpart)  // [plane*8+W][64]
{
    __shared__ float xch[16 * 512]; // 32 KiB
    const int tid = threadIdx.x;
    const int W = tid >> 6, L = tid & 63;
    const int plane = blockIdx.x;
    const int hbase = W * 16 + ((L >> 5) << 3);
    const int wbase = (L & 31) << 2;
    const float* src = in + (size_t)plane * PLANE;

    float v[32];
#pragma unroll
    for (int g = 0; g < 8; ++g) {
        float4 t = *(const float4*)&src[(hbase + g) * 128 + wbase];
        v[4 * g] = t.x; v[4 * g + 1] = t.y; v[4 * g + 2] = t.z; v[4 * g + 3] = t.w;
    }

    fwht2d_reg512(v, xch, W, L);

    float ls0 = 0.f, ls1 = 0.f, ls2 = 0.f, ls3 = 0.f;
#pragma unroll
    for (int g = 0; g < 8; ++g) {
        int rowoff = (hbase + g) * 128 + wbase;
        float4 vm = *(const float4*)&vmat[rowoff];
        float4 tm = *(const float4*)&tmat[rowoff];
        float y0 = v[4 * g]     * vm.x;
        float y1 = v[4 * g + 1] * vm.y;
        float y2 = v[4 * g + 2] * vm.z;
        float y3 = v[4 * g + 3] * vm.w;
        y0 = (fabsf(y0) > fabsf(tm.x)) ? y0 : 0.f;
        y1 = (fabsf(y1) > fabsf(tm.y)) ? y1 : 0.f;
        y2 = (fabsf(y2) > fabsf(tm.z)) ? y2 : 0.f;
        y3 = (fabsf(y3) > fabsf(tm.w)) ? y3 : 0.f;
        ls0 += 1.f / (1.f + __expf(-fabsf(y0)));
        ls1 += 1.f / (1.f + __expf(-fabsf(y1)));
        ls2 += 1.f / (1.f + __expf(-fabsf(y2)));
        ls3 += 1.f / (1.f + __expf(-fabsf(y3)));
        v[4 * g] = y0; v[4 * g + 1] = y1; v[4 * g + 2] = y2; v[4 * g + 3] = y3;
    }
#pragma unroll
    for (int m = 16; m <= 32; m <<= 1) {
        ls0 += __shfl_xor(ls0, m);
        ls1 += __shfl_xor(ls1, m);
        ls2 += __shfl_xor(ls2, m);
        ls3 += __shfl_xor(ls3, m);
    }
    if (L < 16) {
        float4 o; o.x = ls0; o.y = ls1; o.z = ls2; o.w = ls3;
        *(float4*)&klpart[(size_t)(plane * 8 + W) * 64 + 4 * L] = o;
    }

    fwht2d_reg512(v, xch, W, L);

    float* dst = outInv + (size_t)plane * PLANE;
    const float s = 1.f / 16384.f;
#pragma unroll
    for (int g = 0; g < 8; ++g) {
        int h = hbase + g;
        int rowoff = h * 128 + wbase;
        bool rv = h < 122;
        float4 ad = make_float4(0.f, 0.f, 0.f, 0.f);
        if (ADDPOST) ad = *(const float4*)&addbuf[(size_t)plane * PLANE + rowoff];
        float4 o;
        o.x = (rv && wbase + 0 < 122) ? fmaf(v[4 * g],     s, ad.x) : 0.f;
        o.y = (rv && wbase + 1 < 122) ? fmaf(v[4 * g + 1], s, ad.y) : 0.f;
        o.z = (rv && wbase + 2 < 122) ? fmaf(v[4 * g + 2], s, ad.z) : 0.f;
        o.w = (rv && wbase + 3 < 122) ? fmaf(v[4 * g + 3], s, ad.w) : 0.f;
        *(float4*)&dst[rowoff] = o;
    }
}

// ---------------- weight prep ----------------
__global__ void prep_weights(const float* __restrict__ w3, const float* __restrict__ w4,
                             float* __restrict__ w3c, float* __restrict__ w4p)
{
    int tid = blockIdx.x * 256 + threadIdx.x;
    if (tid < 784) {
        int oc = tid / 196;
        int rem = tid - oc * 196;
        int ic = rem / 49;
        int k = rem - ic * 49;
        int kh = k / 7, kw = k - kh * 7;
        w3c[(oc * 4 + ic) * 49 + k] = w3[(ic * 4 + oc) * 49 + (6 - kh) * 7 + (6 - kw)];
    }
    if (tid < 1024) {
        int u = tid & 7, t = (tid >> 3) & 7, pb = (tid >> 6) & 1, pa = (tid >> 7) & 1, ic = tid >> 8;
        int kh = 2 * t + (pa ? 0 : 1);
        int kw = 2 * u + (pb ? 0 : 1);
        w4p[tid] = w4[ic * 256 + kh * 16 + kw];
    }
}

// ---------------- conv1: 1->4, k16, s2, p1 (parity-split tile) ----------------
__global__ __launch_bounds__(256) void conv1_kernel(
    const float* __restrict__ x, const float* __restrict__ w1,
    const float* __restrict__ b1, float* __restrict__ out)
{
    __shared__ float tile[2][78][44];
    int tx = blockIdx.x, ty = blockIdx.y, b = blockIdx.z;
    int tid = threadIdx.x;
    const float* xp = x + (size_t)b * 65536;
    int r0g = ty * 64 - 1, c0g = tx * 64 - 1;
    for (int i = tid; i < 78 * 78; i += 256) {
        int rr = i / 78, cc = i - rr * 78;
        int gi = r0g + rr, gj = c0g + cc;
        float v = (gi >= 0 && gi < 256 && gj >= 0 && gj < 256) ? xp[gi * 256 + gj] : 0.f;
        tile[cc & 1][rr][cc >> 1] = v;
    }
    __syncthreads();
    int cg = tid & 7, r = tid >> 3;
    int B = cg * 4;
    float acc[4][4];
#pragma unroll
    for (int oc = 0; oc < 4; ++oc)
#pragma unroll
        for (int c = 0; c < 4; ++c) acc[oc][c] = 0.f;
#pragma unroll 1
    for (int kh = 0; kh < 16; ++kh) {
        float win[2][12];
        const float* te = &tile[0][2 * r + kh][B];
        const float* to = &tile[1][2 * r + kh][B];
#pragma unroll
        for (int k = 0; k < 3; ++k) {
            *(float4*)&win[0][4 * k] = *(const float4*)&te[4 * k];
            *(float4*)&win[1][4 * k] = *(const float4*)&to[4 * k];
        }
#pragma unroll
        for (int oc = 0; oc < 4; ++oc) {
            const float* wr = w1 + oc * 256 + kh * 16;
#pragma unroll
            for (int kw = 0; kw < 16; ++kw) {
                float wv = wr[kw];
                const float* wp8 = win[kw & 1];
                int q = kw >> 1;
#pragma unroll
                for (int c = 0; c < 4; ++c)
                    acc[oc][c] = fmaf(wp8[c + q], wv, acc[oc][c]);
            }
        }
    }
    int oh = ty * 32 + r;
    int owb = tx * 32 + B;
    bool rowv = oh < 122;
#pragma unroll
    for (int oc = 0; oc < 4; ++oc) {
        float bv = b1[oc];
        float4 res;
        res.x = (rowv && owb + 0 < 122) ? acc[oc][0] + bv : 0.f;
        res.y = (rowv && owb + 1 < 122) ? acc[oc][1] + bv : 0.f;
        res.z = (rowv && owb + 2 < 122) ? acc[oc][2] + bv : 0.f;
        res.w = (rowv && owb + 3 < 122) ? acc[oc][3] + bv : 0.f;
        *(float4*)&out[(((size_t)b * 4 + oc) << 14) + (oh << 7) + owb] = res;
    }
}

// ---------------- 7x7 conv, 4->4, pad 3 ----------------
__global__ __launch_bounds__(256) void conv7_kernel(
    const float* __restrict__ in, const float* __restrict__ w,
    const float* __restrict__ bias, const float* __restrict__ skip,
    float* __restrict__ out)
{
    __shared__ float tile[4][38][40];
    int tx = blockIdx.x, ty = blockIdx.y, b = blockIdx.z;
    int tid = threadIdx.x;
    int r0g = ty * 32 - 3, c0g = tx * 32 - 3;
    for (int i = tid; i < 4 * 38 * 38; i += 256) {
        int ic = i / 1444;
        int rem = i - ic * 1444;
        int rr = rem / 38, cc = rem - rr * 38;
        int gi = r0g + rr, gj = c0g + cc;
        float v = 0.f;
        if (gi >= 0 && gi < 128 && gj >= 0 && gj < 128)
            v = in[(((size_t)b * 4 + ic) << 14) + (gi << 7) + gj];
        tile[ic][rr][cc] = v;
    }
    __syncthreads();
    int cg = tid & 7, r = tid >> 3;
    int B = cg * 4;
    float acc[4][4];
#pragma unroll
    for (int oc = 0; oc < 4; ++oc)
#pragma unroll
        for (int c = 0; c < 4; ++c) acc[oc][c] = 0.f;
#pragma unroll 1
    for (int ic = 0; ic < 4; ++ic) {
#pragma unroll 1
        for (int kh = 0; kh < 7; ++kh) {
            float win[12];
            const float* trow = &tile[ic][r + kh][B];
#pragma unroll
            for (int k = 0; k < 3; ++k)
                *(float4*)&win[4 * k] = *(const float4*)&trow[4 * k];
#pragma unroll
            for (int oc = 0; oc < 4; ++oc) {
                const float* wr = w + (oc * 4 + ic) * 49 + kh * 7;
#pragma unroll
                for (int kw = 0; kw < 7; ++kw) {
                    float wv = wr[kw];
#pragma unroll
                    for (int c = 0; c < 4; ++c)
                        acc[oc][c] = fmaf(win[c + kw], wv, acc[oc][c]);
                }
            }
        }
    }
    int oh = ty * 32 + r;
    int owb = tx * 32 + B;
    bool rowv = oh < 122;
#pragma unroll
    for (int oc = 0; oc < 4; ++oc) {
        size_t o = (((size_t)b * 4 + oc) << 14) + (oh << 7) + owb;
        float4 sv = make_float4(0.f, 0.f, 0.f, 0.f);
        if (skip) sv = *(const float4*)&skip[o];
        float bv = bias[oc];
        float4 res;
        res.x = (rowv && owb + 0 < 122) ? acc[oc][0] + bv + sv.x : 0.f;
        res.y = (rowv && owb + 1 < 122) ? acc[oc][1] + bv + sv.y : 0.f;
        res.z = (rowv && owb + 2 < 122) ? acc[oc][2] + bv + sv.z : 0.f;
        res.w = (rowv && owb + 3 < 122) ? acc[oc][3] + bv + sv.w : 0.f;
        *(float4*)&out[o] = res;
    }
}

// ---------------- convT4: 4->1, k16, s2, p1, 2-channel staged LDS + fused interior TV ----------------
#define CT_HALF(T, ROW, PA)                                                    \
    _Pragma("unroll")                                                          \
    for (int pb = 0; pb < 2; ++pb) {                                           \
        const float* w8 = wp + (((ic * 2 + (PA)) * 2 + pb) * 8 + (T)) * 8;     \
        _Pragma("unroll")                                                      \
        for (int u = 0; u < 8; ++u) {                                          \
            float wv = w8[u];                                                  \
            _Pragma("unroll")                                                  \
            for (int c = 0; c < 4; ++c)                                        \
                acc[PA][pb][c] = fmaf(ROW[8 + c + pb - u], wv, acc[PA][pb][c]);\
        }                                                                      \
    }

#define LOADROW(BUF, R)                                                        \
    _Pragma("unroll")                                                          \
    for (int k = 0; k < 4; ++k)                                                \
        *(float4*)&BUF[4 * k] = *(const float4*)&tld[(R) * 44 + 4 * cg + 4 * k];

__global__ __launch_bounds__(256) void convt4_kernel(
    const float* __restrict__ in, const float* __restrict__ wp,
    const float* __restrict__ bias, const float* __restrict__ xin,
    float* __restrict__ out, float* __restrict__ tvpart)
{
    __shared__ float sbuf[4224];   // 16896 B: stage tile (2*40*44=3520) / TV tile (64*66=4224)
    float (*tile)[40][44] = (float(*)[40][44])sbuf;
    int tx = blockIdx.x, ty = blockIdx.y, b = blockIdx.z;
    int tid = threadIdx.x;
    int A0 = ty * 32, B0 = tx * 32;
    int r0g = A0 - 7, c0g = B0 - 8;
    int cg = tid & 7, ra = tid >> 3;
    float acc[2][2][4];
#pragma unroll
    for (int pa = 0; pa < 2; ++pa)
#pragma unroll
        for (int pb = 0; pb < 2; ++pb)
#pragma unroll
            for (int c = 0; c < 4; ++c) acc[pa][pb][c] = 0.f;

#pragma unroll 1
    for (int icp = 0; icp < 2; ++icp) {
        __syncthreads();
        for (int i = tid; i < 2 * 40 * 44; i += 256) {
            int ics = i / 1760;
            int rem = i - ics * 1760;
            int rr = rem / 44, cc = rem - rr * 44;
            int gi = r0g + rr, gj = c0g + cc;
            int icg = icp * 2 + ics;
            float v = 0.f;
            if (gi >= 0 && gi < 128 && gj >= 0 && gj < 128)
                v = in[(((size_t)b * 4 + icg) << 14) + (gi << 7) + gj];
            tile[ics][rr][cc] = v;
        }
        __syncthreads();
#pragma unroll 1
        for (int ics = 0; ics < 2; ++ics) {
            const int ic = icp * 2 + ics;
            const float* tld = &tile[ics][0][0];
            float bufA[16], bufB[16];
            LOADROW(bufB, ra + 8)
#pragma unroll 1
            for (int t2 = 0; t2 < 8; t2 += 2) {
                LOADROW(bufA, ra + 7 - t2)
                CT_HALF(t2, bufA, 0)
                CT_HALF(t2, bufB, 1)
                LOADROW(bufB, ra + 6 - t2)
                CT_HALF(t2 + 1, bufB, 0)
                CT_HALF(t2 + 1, bufA, 1)
            }
        }
    }
    int oh0 = 2 * (A0 + ra);
    int owb = 2 * (B0 + 4 * cg);
    float bv = bias[0];
    float4 res[2][2];
#pragma unroll
    for (int pa = 0; pa < 2; ++pa) {
        size_t o = (size_t)b * 65536 + (size_t)(oh0 + pa) * 256 + owb;
        float4 x0 = *(const float4*)&xin[o];
        float4 x1 = *(const float4*)&xin[o + 4];
        float4 r0, r1;
        r0.x = (acc[pa][0][0] + bv) * x0.x;
        r0.y = (acc[pa][1][0] + bv) * x0.y;
        r0.z = (acc[pa][0][1] + bv) * x0.z;
        r0.w = (acc[pa][1][1] + bv) * x0.w;
        r1.x = (acc[pa][0][2] + bv) * x1.x;
        r1.y = (acc[pa][1][2] + bv) * x1.y;
        r1.z = (acc[pa][0][3] + bv) * x1.z;
        r1.w = (acc[pa][1][3] + bv) * x1.w;
        *(float4*)&out[o] = r0;
        *(float4*)&out[o + 4] = r1;
        res[pa][0] = r0; res[pa][1] = r1;
    }

    // ---- fused interior TV over this block's 64x64 output tile ----
    __syncthreads();   // done with stage-tile reads
    int lr0 = 2 * ra, lc = 8 * cg;
#pragma unroll
    for (int pa = 0; pa < 2; ++pa) {
        *(float4*)&sbuf[(lr0 + pa) * 66 + lc]     = res[pa][0];
        *(float4*)&sbuf[(lr0 + pa) * 66 + lc + 4] = res[pa][1];
    }
    __syncthreads();
    float local = 0.f;
#pragma unroll 1
    for (int i = tid; i < 1024; i += 256) {
        int rr = i >> 4, c4 = (i & 15) << 2;
        float4 a = *(const float4*)&sbuf[rr * 66 + c4];
        local += fabsf(a.y - a.x) + fabsf(a.z - a.y) + fabsf(a.w - a.z);
        if (c4 < 60) local += fabsf(sbuf[rr * 66 + c4 + 4] - a.w);
        if (rr < 63) {
            float4 d = *(const float4*)&sbuf[(rr + 1) * 66 + c4];
            local += fabsf(d.x - a.x) + fabsf(d.y - a.y) + fabsf(d.z - a.z) + fabsf(d.w - a.w);
        }
    }
#pragma unroll
    for (int off = 32; off > 0; off >>= 1) local += __shfl_down(local, off);
    __syncthreads();
    if ((tid & 63) == 0) sbuf[tid >> 6] = local;
    __syncthreads();
    if (tid == 0) {
        int bid = (b * 4 + ty) * 4 + tx;
        tvpart[bid] = sbuf[0] + sbuf[1] + sbuf[2] + sbuf[3];
    }
}

// ---------------- stage-1 reduce: KL [3][4096][64] -> [3][16][64]; TV partials + boundary ----------------
__global__ __launch_bounds__(256) void reduce1_kernel(
    const float* __restrict__ klpart, const float* __restrict__ tvpart,
    const float* __restrict__ out,
    float* __restrict__ klred, float* __restrict__ tvred)
{
    int bid = blockIdx.x;
    int tid = threadIdx.x;
    if (bid < 48) {
        int layer = bid >> 4, chunk = bid & 15;
        int sub = tid >> 6, t = tid & 63;
        const float* base = klpart + (size_t)layer * 262144 + (size_t)chunk * 256 * 64;
        float s = 0.f;
        for (int r = sub; r < 256; r += 4)
            s += base[r * 64 + t];
        __shared__ float red[4][64];
        red[sub][t] = s;
        __syncthreads();
        if (tid < 64)
            klred[(layer * 16 + chunk) * 64 + tid] =
                red[0][tid] + red[1][tid] + red[2][tid] + red[3][tid];
    } else if (bid == 48) {
        __shared__ float red[256];
        float s = 0.f;
        for (int i = tid; i < 2048; i += 256) s += tvpart[i];
        red[tid] = s;
        __syncthreads();
        for (int st = 128; st > 0; st >>= 1) {
            if (tid < st) red[tid] += red[tid + st];
            __syncthreads();
        }
        if (tid == 0) tvred[0] = red[0];
    } else {
        // boundary TV pairs at tile seams h,w in {63,127,191}: 196608 pairs over 8 blocks
        int blockn = bid - 49;   // [0,8)
        __shared__ float red[256];
        float s = 0.f;
        for (int p = blockn * 24576 + tid; p < (blockn + 1) * 24576; p += 256) {
            if (p < 98304) {
                int j = p >> 15, rem = p & 32767;
                int b = rem >> 8, k = rem & 255;
                int h = 63 + 64 * j;
                size_t o = (size_t)b * 65536 + (size_t)h * 256 + k;
                s += fabsf(out[o + 256] - out[o]);
            } else {
                int q = p - 98304;
                int j = q >> 15, rem = q & 32767;
                int b = rem >> 8, h = rem & 255;
                int w = 63 + 64 * j;
                size_t o = (size_t)b * 65536 + (size_t)h * 256 + w;
                s += fabsf(out[o + 1] - out[o]);
            }
        }
        red[tid] = s;
        __syncthreads();
        for (int st = 128; st > 0; st >>= 1) {
            if (tid < st) red[tid] += red[tid + st];
            __syncthreads();
        }
        if (tid == 0) tvred[1 + blockn] = red[0];
    }
}

// ---------------- stage-2 finalize ----------------
__global__ __launch_bounds__(64) void finalize2_kernel(
    const float* __restrict__ klred, const float* __restrict__ tvred,
    float* __restrict__ lossout)
{
    int t = threadIdx.x;
    float p = 1.f / (1.f + __expf(-0.001f));
    float term = 0.f;
#pragma unroll
    for (int l = 0; l < 3; ++l) {
        float q = 0.f;
#pragma unroll
        for (int c = 0; c < 16; ++c)
            q += klred[(l * 16 + c) * 64 + t];
        float qm = q * (1.f / 131072.f);
        term += p * logf(p / qm) + (1.f - p) * logf((1.f - p) / (1.f - qm));
    }
#pragma unroll
    for (int off = 32; off > 0; off >>= 1)
        term += __shfl_down(term, off);
    if (t == 0) {
        float tv = 0.f;
#pragma unroll
        for (int i = 0; i < 9; ++i) tv += tvred[i];
        lossout[0] = 0.05f * tv / 8388608.f + 0.1f * term;
    }
}

extern "C" void kernel_launch(void* const* d_in, const int* in_sizes, int n_in,
                              void* d_out, int out_size, void* d_ws, size_t ws_size,
                              hipStream_t stream) {
    (void)in_sizes; (void)n_in; (void)out_size; (void)ws_size;
    const float* x  = (const float*)d_in[0];
    const float* v1 = (const float*)d_in[2];
    const float* T1 = (const float*)d_in[3];
    const float* v2 = (const float*)d_in[4];
    const float* T2 = (const float*)d_in[5];
    const float* v3 = (const float*)d_in[6];
    const float* T3 = (const float*)d_in[7];
    const float* w1 = (const float*)d_in[8];
    const float* b1 = (const float*)d_in[9];
    const float* w2 = (const float*)d_in[10];
    const float* b2 = (const float*)d_in[11];
    const float* w3 = (const float*)d_in[12];
    const float* b3 = (const float*)d_in[13];
    const float* w4 = (const float*)d_in[14];
    const float* b4 = (const float*)d_in[15];
    float* out = (float*)d_out;

    float* W0 = (float*)d_ws;
    float* W1 = W0 + (size_t)NPLANES * PLANE;
    float* W2 = W1 + (size_t)NPLANES * PLANE;
    float* klpart = W2 + (size_t)NPLANES * PLANE; // [3][4096][64]
    float* tvpart = klpart + 3 * 4096 * 64;        // [2048]
    float* klred  = tvpart + 2048;                  // [3][16][64]
    float* tvred  = klred + 3072;                   // [16]
    float* w3c = tvred + 16;                        // 784
    float* w4p = w3c + 784;                         // 1024
    float* x10buf = out;                            // reuse d_out region as x10 scratch

    prep_weights<<<4, 256, 0, stream>>>(w3, w4, w3c, w4p);
    conv1_kernel<<<dim3(4, 4, 128), 256, 0, stream>>>(x, w1, b1, W0);
    fwht_kernel_t<false><<<NPLANES, 512, 0, stream>>>(W0, v1, T1, nullptr, W1, klpart);
    conv7_kernel<<<dim3(4, 4, 128), 256, 0, stream>>>(W1, w2, b2, nullptr, x10buf);
    fwht_kernel_t<false><<<NPLANES, 512, 0, stream>>>(x10buf, v2, T2, nullptr, W0, klpart + 262144);
    conv7_kernel<<<dim3(4, 4, 128), 256, 0, stream>>>(W0, w3c, b3, x10buf, W2);
    fwht_kernel_t<true><<<NPLANES, 512, 0, stream>>>(W2, v3, T3, W1, W0, klpart + 2 * 262144);
    convt4_kernel<<<dim3(4, 4, 128), 256, 0, stream>>>(W0, w4p, b4, x, out, tvpart);
    reduce1_kernel<<<57, 256, 0, stream>>>(klpart, tvpart, out, klred, tvred);
    finalize2_kernel<<<1, 64, 0, stream>>>(klred, tvred, out + 8388608);
}

// Round 18
// 354.123 us; speedup vs baseline: 1.1184x; 1.1184x over previous
//
#include <hip/hip_runtime.h>
#include <math.h>

#define PLANE 16384   // 128*128
#define NPLANES 512   // B(128) * C(4)

typedef __attribute__((ext_vector_type(2))) unsigned int uint2v;

// ---------------- in-register 2D FWHT-128x128 across a 512-thread block ----------------
// Shuffle-stage pipes: m=1,2 -> DPP quad_perm; m=8 -> DPP row_ror:8 (xor8==rot8 in 16-row);
// m=16/32 -> permlane16/32_swap pair-trick (all VALU). Only m=4 remains on the DS pipe.
__device__ __forceinline__ void fwht2d_reg512(float* __restrict__ v, float* __restrict__ xch,
                                              int W, int L) {
    // w bits 0-1 (reg bits): in-register
#pragma unroll
    for (int m = 1; m <= 2; m <<= 1) {
#pragma unroll
        for (int r = 0; r < 32; ++r) {
            if (!(r & m)) {
                int s = r | m;
                float a = v[r], b = v[s];
                v[r] = a + b; v[s] = a - b;
            }
        }
    }
    // lane mask 1: quad_perm [1,0,3,2] = 0xB1
    {
        float sg = (L & 1) ? -1.f : 1.f;
#pragma unroll
        for (int r = 0; r < 32; ++r) {
            int xi = __float_as_int(v[r]);
            float p = __int_as_float(__builtin_amdgcn_update_dpp(xi, xi, 0xB1, 0xF, 0xF, false));
            v[r] = fmaf(sg, v[r], p);
        }
    }
    // lane mask 2: quad_perm [2,3,0,1] = 0x4E
    {
        float sg = (L & 2) ? -1.f : 1.f;
#pragma unroll
        for (int r = 0; r < 32; ++r) {
            int xi = __float_as_int(v[r]);
            float p = __int_as_float(__builtin_amdgcn_update_dpp(xi, xi, 0x4E, 0xF, 0xF, false));
            v[r] = fmaf(sg, v[r], p);
        }
    }
    // lane mask 4: DS shuffle (no VALU equivalent)
    {
        float sg = (L & 4) ? -1.f : 1.f;
#pragma unroll
        for (int r = 0; r < 32; ++r) {
            float p = __shfl_xor(v[r], 4);
            v[r] = fmaf(sg, v[r], p);
        }
    }
    // lane mask 8: row_ror:8 (0x128)
    {
        float sg = (L & 8) ? -1.f : 1.f;
#pragma unroll
        for (int r = 0; r < 32; ++r) {
            int xi = __float_as_int(v[r]);
            float p = __int_as_float(__builtin_amdgcn_update_dpp(xi, xi, 0x128, 0xF, 0xF, false));
            v[r] = fmaf(sg, v[r], p);
        }
    }
    // lane mask 16: permlane16_swap pair-trick (2 regs per swap-add/sub-swap)
#pragma unroll
    for (int r = 0; r < 32; r += 2) {
        uint2v s1 = __builtin_amdgcn_permlane16_swap(__float_as_uint(v[r]),
                                                     __float_as_uint(v[r + 1]), false, false);
        float u = __uint_as_float(s1.x) + __uint_as_float(s1.y);
        float w = __uint_as_float(s1.x) - __uint_as_float(s1.y);
        uint2v s2 = __builtin_amdgcn_permlane16_swap(__float_as_uint(u),
                                                     __float_as_uint(w), false, false);
        v[r]     = __uint_as_float(s2.x);
        v[r + 1] = __uint_as_float(s2.y);
    }
    // lane mask 32: permlane32_swap pair-trick
#pragma unroll
    for (int r = 0; r < 32; r += 2) {
        uint2v s1 = __builtin_amdgcn_permlane32_swap(__float_as_uint(v[r]),
                                                     __float_as_uint(v[r + 1]), false, false);
        float u = __uint_as_float(s1.x) + __uint_as_float(s1.y);
        float w = __uint_as_float(s1.x) - __uint_as_float(s1.y);
        uint2v s2 = __builtin_amdgcn_permlane32_swap(__float_as_uint(u),
                                                     __float_as_uint(w), false, false);
        v[r]     = __uint_as_float(s2.x);
        v[r + 1] = __uint_as_float(s2.y);
    }
    // h bits 0-2 (reg bits): in-register
#pragma unroll
    for (int m = 4; m <= 16; m <<= 1) {
#pragma unroll
        for (int r = 0; r < 32; ++r) {
            if (!(r & m)) {
                int s = r | m;
                float a = v[r], b = v[s];
                v[r] = a + b; v[s] = a - b;
            }
        }
    }
    // h bits 4-6 (wave index): 3 pairwise LDS stages x 2 reg-halves, conflict-free layout
#pragma unroll
    for (int mw = 1; mw <= 4; mw <<= 1) {
        int Wp = W ^ mw;
        float sg = (W & mw) ? -1.f : 1.f;
#pragma unroll
        for (int half = 0; half < 2; ++half) {
            __syncthreads();
#pragma unroll
            for (int j = 0; j < 16; ++j)
                xch[(j * 8 + W) * 64 + L] = v[half * 16 + j];
            __syncthreads();
#pragma unroll
            for (int j = 0; j < 16; ++j) {
                float p = xch[(j * 8 + Wp) * 64 + L];
                v[half * 16 + j] = fmaf(sg, v[half * 16 + j], p);
            }
        }
    }
}

template <bool ADDPOST>
__global__ __launch_bounds__(512) void fwht_kernel_t(
    const float* __restrict__ in, const float* __restrict__ vmat,
    const float* __restrict__ tmat, const float* __restrict__ addbuf,
    float* __restrict__ outInv, float* __restrict__ klpart)  // [plane*8+W][64]
{
    __shared__ float xch[16 * 512]; // 32 KiB
    const int tid = threadIdx.x;
    const int W = tid >> 6, L = tid & 63;
    const int plane = blockIdx.x;
    const int hbase = W * 16 + ((L >> 5) << 3);
    const int wbase = (L & 31) << 2;
    const float* src = in + (size_t)plane * PLANE;

    float v[32];
#pragma unroll
    for (int g = 0; g < 8; ++g) {
        float4 t = *(const float4*)&src[(hbase + g) * 128 + wbase];
        v[4 * g] = t.x; v[4 * g + 1] = t.y; v[4 * g + 2] = t.z; v[4 * g + 3] = t.w;
    }

    fwht2d_reg512(v, xch, W, L);

    float ls0 = 0.f, ls1 = 0.f, ls2 = 0.f, ls3 = 0.f;
#pragma unroll
    for (int g = 0; g < 8; ++g) {
        int rowoff = (hbase + g) * 128 + wbase;
        float4 vm = *(const float4*)&vmat[rowoff];
        float4 tm = *(const float4*)&tmat[rowoff];
        float y0 = v[4 * g]     * vm.x;
        float y1 = v[4 * g + 1] * vm.y;
        float y2 = v[4 * g + 2] * vm.z;
        float y3 = v[4 * g + 3] * vm.w;
        y0 = (fabsf(y0) > fabsf(tm.x)) ? y0 : 0.f;
        y1 = (fabsf(y1) > fabsf(tm.y)) ? y1 : 0.f;
        y2 = (fabsf(y2) > fabsf(tm.z)) ? y2 : 0.f;
        y3 = (fabsf(y3) > fabsf(tm.w)) ? y3 : 0.f;
        ls0 += 1.f / (1.f + __expf(-fabsf(y0)));
        ls1 += 1.f / (1.f + __expf(-fabsf(y1)));
        ls2 += 1.f / (1.f + __expf(-fabsf(y2)));
        ls3 += 1.f / (1.f + __expf(-fabsf(y3)));
        v[4 * g] = y0; v[4 * g + 1] = y1; v[4 * g + 2] = y2; v[4 * g + 3] = y3;
    }
#pragma unroll
    for (int m = 16; m <= 32; m <<= 1) {
        ls0 += __shfl_xor(ls0, m);
        ls1 += __shfl_xor(ls1, m);
        ls2 += __shfl_xor(ls2, m);
        ls3 += __shfl_xor(ls3, m);
    }
    if (L < 16) {
        float4 o; o.x = ls0; o.y = ls1; o.z = ls2; o.w = ls3;
        *(float4*)&klpart[(size_t)(plane * 8 + W) * 64 + 4 * L] = o;
    }

    fwht2d_reg512(v, xch, W, L);

    float* dst = outInv + (size_t)plane * PLANE;
    const float s = 1.f / 16384.f;
#pragma unroll
    for (int g = 0; g < 8; ++g) {
        int h = hbase + g;
        int rowoff = h * 128 + wbase;
        bool rv = h < 122;
        float4 ad = make_float4(0.f, 0.f, 0.f, 0.f);
        if (ADDPOST) ad = *(const float4*)&addbuf[(size_t)plane * PLANE + rowoff];
        float4 o;
        o.x = (rv && wbase + 0 < 122) ? fmaf(v[4 * g],     s, ad.x) : 0.f;
        o.y = (rv && wbase + 1 < 122) ? fmaf(v[4 * g + 1], s, ad.y) : 0.f;
        o.z = (rv && wbase + 2 < 122) ? fmaf(v[4 * g + 2], s, ad.z) : 0.f;
        o.w = (rv && wbase + 3 < 122) ? fmaf(v[4 * g + 3], s, ad.w) : 0.f;
        *(float4*)&dst[rowoff] = o;
    }
}

// ---------------- weight prep ----------------
__global__ void prep_weights(const float* __restrict__ w3, const float* __restrict__ w4,
                             float* __restrict__ w3c, float* __restrict__ w4p)
{
    int tid = blockIdx.x * 256 + threadIdx.x;
    if (tid < 784) {
        int oc = tid / 196;
        int rem = tid - oc * 196;
        int ic = rem / 49;
        int k = rem - ic * 49;
        int kh = k / 7, kw = k - kh * 7;
        w3c[(oc * 4 + ic) * 49 + k] = w3[(ic * 4 + oc) * 49 + (6 - kh) * 7 + (6 - kw)];
    }
    if (tid < 1024) {
        int u = tid & 7, t = (tid >> 3) & 7, pb = (tid >> 6) & 1, pa = (tid >> 7) & 1, ic = tid >> 8;
        int kh = 2 * t + (pa ? 0 : 1);
        int kw = 2 * u + (pb ? 0 : 1);
        w4p[tid] = w4[ic * 256 + kh * 16 + kw];
    }
}

// ---------------- conv1: 1->4, k16, s2, p1 (parity-split tile) ----------------
__global__ __launch_bounds__(256) void conv1_kernel(
    const float* __restrict__ x, const float* __restrict__ w1,
    const float* __restrict__ b1, float* __restrict__ out)
{
    __shared__ float tile[2][78][44];
    int tx = blockIdx.x, ty = blockIdx.y, b = blockIdx.z;
    int tid = threadIdx.x;
    const float* xp = x + (size_t)b * 65536;
    int r0g = ty * 64 - 1, c0g = tx * 64 - 1;
    for (int i = tid; i < 78 * 78; i += 256) {
        int rr = i / 78, cc = i - rr * 78;
        int gi = r0g + rr, gj = c0g + cc;
        float v = (gi >= 0 && gi < 256 && gj >= 0 && gj < 256) ? xp[gi * 256 + gj] : 0.f;
        tile[cc & 1][rr][cc >> 1] = v;
    }
    __syncthreads();
    int cg = tid & 7, r = tid >> 3;
    int B = cg * 4;
    float acc[4][4];
#pragma unroll
    for (int oc = 0; oc < 4; ++oc)
#pragma unroll
        for (int c = 0; c < 4; ++c) acc[oc][c] = 0.f;
#pragma unroll 1
    for (int kh = 0; kh < 16; ++kh) {
        float win[2][12];
        const float* te = &tile[0][2 * r + kh][B];
        const float* to = &tile[1][2 * r + kh][B];
#pragma unroll
        for (int k = 0; k < 3; ++k) {
            *(float4*)&win[0][4 * k] = *(const float4*)&te[4 * k];
            *(float4*)&win[1][4 * k] = *(const float4*)&to[4 * k];
        }
#pragma unroll
        for (int oc = 0; oc < 4; ++oc) {
            const float* wr = w1 + oc * 256 + kh * 16;
#pragma unroll
            for (int kw = 0; kw < 16; ++kw) {
                float wv = wr[kw];
                const float* wp8 = win[kw & 1];
                int q = kw >> 1;
#pragma unroll
                for (int c = 0; c < 4; ++c)
                    acc[oc][c] = fmaf(wp8[c + q], wv, acc[oc][c]);
            }
        }
    }
    int oh = ty * 32 + r;
    int owb = tx * 32 + B;
    bool rowv = oh < 122;
#pragma unroll
    for (int oc = 0; oc < 4; ++oc) {
        float bv = b1[oc];
        float4 res;
        res.x = (rowv && owb + 0 < 122) ? acc[oc][0] + bv : 0.f;
        res.y = (rowv && owb + 1 < 122) ? acc[oc][1] + bv : 0.f;
        res.z = (rowv && owb + 2 < 122) ? acc[oc][2] + bv : 0.f;
        res.w = (rowv && owb + 3 < 122) ? acc[oc][3] + bv : 0.f;
        *(float4*)&out[(((size_t)b * 4 + oc) << 14) + (oh << 7) + owb] = res;
    }
}

// ---------------- 7x7 conv, 4->4, pad 3 ----------------
__global__ __launch_bounds__(256) void conv7_kernel(
    const float* __restrict__ in, const float* __restrict__ w,
    const float* __restrict__ bias, const float* __restrict__ skip,
    float* __restrict__ out)
{
    __shared__ float tile[4][38][40];
    int tx = blockIdx.x, ty = blockIdx.y, b = blockIdx.z;
    int tid = threadIdx.x;
    int r0g = ty * 32 - 3, c0g = tx * 32 - 3;
    for (int i = tid; i < 4 * 38 * 38; i += 256) {
        int ic = i / 1444;
        int rem = i - ic * 1444;
        int rr = rem / 38, cc = rem - rr * 38;
        int gi = r0g + rr, gj = c0g + cc;
        float v = 0.f;
        if (gi >= 0 && gi < 128 && gj >= 0 && gj < 128)
            v = in[(((size_t)b * 4 + ic) << 14) + (gi << 7) + gj];
        tile[ic][rr][cc] = v;
    }
    __syncthreads();
    int cg = tid & 7, r = tid >> 3;
    int B = cg * 4;
    float acc[4][4];
#pragma unroll
    for (int oc = 0; oc < 4; ++oc)
#pragma unroll
        for (int c = 0; c < 4; ++c) acc[oc][c] = 0.f;
#pragma unroll 1
    for (int ic = 0; ic < 4; ++ic) {
#pragma unroll 1
        for (int kh = 0; kh < 7; ++kh) {
            float win[12];
            const float* trow = &tile[ic][r + kh][B];
#pragma unroll
            for (int k = 0; k < 3; ++k)
                *(float4*)&win[4 * k] = *(const float4*)&trow[4 * k];
#pragma unroll
            for (int oc = 0; oc < 4; ++oc) {
                const float* wr = w + (oc * 4 + ic) * 49 + kh * 7;
#pragma unroll
                for (int kw = 0; kw < 7; ++kw) {
                    float wv = wr[kw];
#pragma unroll
                    for (int c = 0; c < 4; ++c)
                        acc[oc][c] = fmaf(win[c + kw], wv, acc[oc][c]);
                }
            }
        }
    }
    int oh = ty * 32 + r;
    int owb = tx * 32 + B;
    bool rowv = oh < 122;
#pragma unroll
    for (int oc = 0; oc < 4; ++oc) {
        size_t o = (((size_t)b * 4 + oc) << 14) + (oh << 7) + owb;
        float4 sv = make_float4(0.f, 0.f, 0.f, 0.f);
        if (skip) sv = *(const float4*)&skip[o];
        float bv = bias[oc];
        float4 res;
        res.x = (rowv && owb + 0 < 122) ? acc[oc][0] + bv + sv.x : 0.f;
        res.y = (rowv && owb + 1 < 122) ? acc[oc][1] + bv + sv.y : 0.f;
        res.z = (rowv && owb + 2 < 122) ? acc[oc][2] + bv + sv.z : 0.f;
        res.w = (rowv && owb + 3 < 122) ? acc[oc][3] + bv + sv.w : 0.f;
        *(float4*)&out[o] = res;
    }
}

// ---------------- convT4: 4->1, k16, s2, p1, parity-decomposed; 2-channel staged LDS ----------------
#define CT_HALF(T, ROW, PA)                                                    \
    _Pragma("unroll")                                                          \
    for (int pb = 0; pb < 2; ++pb) {                                           \
        const float* w8 = wp + (((ic * 2 + (PA)) * 2 + pb) * 8 + (T)) * 8;     \
        _Pragma("unroll")                                                      \
        for (int u = 0; u < 8; ++u) {                                          \
            float wv = w8[u];                                                  \
            _Pragma("unroll")                                                  \
            for (int c = 0; c < 4; ++c)                                        \
                acc[PA][pb][c] = fmaf(ROW[8 + c + pb - u], wv, acc[PA][pb][c]);\
        }                                                                      \
    }

#define LOADROW(BUF, R)                                                        \
    _Pragma("unroll")                                                          \
    for (int k = 0; k < 4; ++k)                                                \
        *(float4*)&BUF[4 * k] = *(const float4*)&tld[(R) * 44 + 4 * cg + 4 * k];

__global__ __launch_bounds__(256) void convt4_kernel(
    const float* __restrict__ in, const float* __restrict__ wp,
    const float* __restrict__ bias, const float* __restrict__ xin,
    float* __restrict__ out)
{
    __shared__ float tile[2][40][44];   // 14080 B
    int tx = blockIdx.x, ty = blockIdx.y, b = blockIdx.z;
    int tid = threadIdx.x;
    int A0 = ty * 32, B0 = tx * 32;
    int r0g = A0 - 7, c0g = B0 - 8;
    int cg = tid & 7, ra = tid >> 3;
    float acc[2][2][4];
#pragma unroll
    for (int pa = 0; pa < 2; ++pa)
#pragma unroll
        for (int pb = 0; pb < 2; ++pb)
#pragma unroll
            for (int c = 0; c < 4; ++c) acc[pa][pb][c] = 0.f;

#pragma unroll 1
    for (int icp = 0; icp < 2; ++icp) {
        __syncthreads();
        for (int i = tid; i < 2 * 40 * 44; i += 256) {
            int ics = i / 1760;
            int rem = i - ics * 1760;
            int rr = rem / 44, cc = rem - rr * 44;
            int gi = r0g + rr, gj = c0g + cc;
            int icg = icp * 2 + ics;
            float v = 0.f;
            if (gi >= 0 && gi < 128 && gj >= 0 && gj < 128)
                v = in[(((size_t)b * 4 + icg) << 14) + (gi << 7) + gj];
            tile[ics][rr][cc] = v;
        }
        __syncthreads();
#pragma unroll 1
        for (int ics = 0; ics < 2; ++ics) {
            const int ic = icp * 2 + ics;
            const float* tld = &tile[ics][0][0];
            float bufA[16], bufB[16];
            LOADROW(bufB, ra + 8)
#pragma unroll 1
            for (int t2 = 0; t2 < 8; t2 += 2) {
                LOADROW(bufA, ra + 7 - t2)
                CT_HALF(t2, bufA, 0)
                CT_HALF(t2, bufB, 1)
                LOADROW(bufB, ra + 6 - t2)
                CT_HALF(t2 + 1, bufB, 0)
                CT_HALF(t2 + 1, bufA, 1)
            }
        }
    }
    int oh0 = 2 * (A0 + ra);
    int owb = 2 * (B0 + 4 * cg);
    float bv = bias[0];
#pragma unroll
    for (int pa = 0; pa < 2; ++pa) {
        size_t o = (size_t)b * 65536 + (size_t)(oh0 + pa) * 256 + owb;
        float4 x0 = *(const float4*)&xin[o];
        float4 x1 = *(const float4*)&xin[o + 4];
        float4 r0, r1;
        r0.x = (acc[pa][0][0] + bv) * x0.x;
        r0.y = (acc[pa][1][0] + bv) * x0.y;
        r0.z = (acc[pa][0][1] + bv) * x0.z;
        r0.w = (acc[pa][1][1] + bv) * x0.w;
        r1.x = (acc[pa][0][2] + bv) * x1.x;
        r1.y = (acc[pa][1][2] + bv) * x1.y;
        r1.z = (acc[pa][0][3] + bv) * x1.z;
        r1.w = (acc[pa][1][3] + bv) * x1.w;
        *(float4*)&out[o] = r0;
        *(float4*)&out[o + 4] = r1;
    }
}

// ---------------- TV loss (vectorized, per-block partial, no atomics) ----------------
__global__ __launch_bounds__(256) void tv_kernel(
    const float* __restrict__ out, float* __restrict__ tvpart)
{
    const float4* out4 = (const float4*)out;
    __shared__ float red[256];
    int tid = threadIdx.x;
    float local = 0.f;
    const int total4 = 128 * 65536 / 4;
    for (int i4 = blockIdx.x * 256 + tid; i4 < total4; i4 += gridDim.x * 256) {
        float4 a = out4[i4];
        int i = i4 << 2;
        local += fabsf(a.y - a.x) + fabsf(a.z - a.y) + fabsf(a.w - a.z);
        if ((i & 255) != 252) local += fabsf(out[i + 4] - a.w);
        if ((i & 65535) < 65280) {
            float4 c = out4[i4 + 64];
            local += fabsf(c.x - a.x) + fabsf(c.y - a.y) + fabsf(c.z - a.z) + fabsf(c.w - a.w);
        }
    }
    red[tid] = local;
    __syncthreads();
    for (int s = 128; s > 0; s >>= 1) {
        if (tid < s) red[tid] += red[tid + s];
        __syncthreads();
    }
    if (tid == 0) tvpart[blockIdx.x] = red[0];
}

// ---------------- stage-1 reduce: KL partials [3][4096][64] -> [3][16][64]; TV [2048] -> [1] ----------------
__global__ __launch_bounds__(256) void reduce1_kernel(
    const float* __restrict__ klpart, const float* __restrict__ tvpart,
    float* __restrict__ klred, float* __restrict__ tvred)
{
    int bid = blockIdx.x;
    int tid = threadIdx.x;
    if (bid < 48) {
        int layer = bid >> 4, chunk = bid & 15;
        int sub = tid >> 6, t = tid & 63;
        const float* base = klpart + (size_t)layer * 262144 + (size_t)chunk * 256 * 64;
        float s = 0.f;
        for (int r = sub; r < 256; r += 4)
            s += base[r * 64 + t];
        __shared__ float red[4][64];
        red[sub][t] = s;
        __syncthreads();
        if (tid < 64)
            klred[(layer * 16 + chunk) * 64 + tid] =
                red[0][tid] + red[1][tid] + red[2][tid] + red[3][tid];
    } else {
        __shared__ float red[256];
        float s = 0.f;
        for (int i = tid; i < 2048; i += 256) s += tvpart[i];
        red[tid] = s;
        __syncthreads();
        for (int st = 128; st > 0; st >>= 1) {
            if (tid < st) red[tid] += red[tid + st];
            __syncthreads();
        }
        if (tid == 0) tvred[0] = red[0];
    }
}

// ---------------- stage-2 finalize ----------------
__global__ __launch_bounds__(64) void finalize2_kernel(
    const float* __restrict__ klred, const float* __restrict__ tvred,
    float* __restrict__ lossout)
{
    int t = threadIdx.x;
    float p = 1.f / (1.f + __expf(-0.001f));
    float term = 0.f;
#pragma unroll
    for (int l = 0; l < 3; ++l) {
        float q = 0.f;
#pragma unroll
        for (int c = 0; c < 16; ++c)
            q += klred[(l * 16 + c) * 64 + t];
        float qm = q * (1.f / 131072.f);
        term += p * logf(p / qm) + (1.f - p) * logf((1.f - p) / (1.f - qm));
    }
#pragma unroll
    for (int off = 32; off > 0; off >>= 1)
        term += __shfl_down(term, off);
    if (t == 0)
        lossout[0] = 0.05f * tvred[0] / 8388608.f + 0.1f * term;
}

extern "C" void kernel_launch(void* const* d_in, const int* in_sizes, int n_in,
                              void* d_out, int out_size, void* d_ws, size_t ws_size,
                              hipStream_t stream) {
    (void)in_sizes; (void)n_in; (void)out_size; (void)ws_size;
    const float* x  = (const float*)d_in[0];
    const float* v1 = (const float*)d_in[2];
    const float* T1 = (const float*)d_in[3];
    const float* v2 = (const float*)d_in[4];
    const float* T2 = (const float*)d_in[5];
    const float* v3 = (const float*)d_in[6];
    const float* T3 = (const float*)d_in[7];
    const float* w1 = (const float*)d_in[8];
    const float* b1 = (const float*)d_in[9];
    const float* w2 = (const float*)d_in[10];
    const float* b2 = (const float*)d_in[11];
    const float* w3 = (const float*)d_in[12];
    const float* b3 = (const float*)d_in[13];
    const float* w4 = (const float*)d_in[14];
    const float* b4 = (const float*)d_in[15];
    float* out = (float*)d_out;

    float* W0 = (float*)d_ws;
    float* W1 = W0 + (size_t)NPLANES * PLANE;
    float* W2 = W1 + (size_t)NPLANES * PLANE;
    float* klpart = W2 + (size_t)NPLANES * PLANE; // [3][4096][64]
    float* tvpart = klpart + 3 * 4096 * 64;        // [2048]
    float* klred  = tvpart + 2048;                  // [3][16][64]
    float* tvred  = klred + 3072;                   // [1]
    float* w3c = tvred + 64;                        // 784
    float* w4p = w3c + 784;                         // 1024
    float* x10buf = out;                            // reuse d_out region as x10 scratch

    prep_weights<<<4, 256, 0, stream>>>(w3, w4, w3c, w4p);
    conv1_kernel<<<dim3(4, 4, 128), 256, 0, stream>>>(x, w1, b1, W0);
    fwht_kernel_t<false><<<NPLANES, 512, 0, stream>>>(W0, v1, T1, nullptr, W1, klpart);
    conv7_kernel<<<dim3(4, 4, 128), 256, 0, stream>>>(W1, w2, b2, nullptr, x10buf);
    fwht_kernel_t<false><<<NPLANES, 512, 0, stream>>>(x10buf, v2, T2, nullptr, W0, klpart + 262144);
    conv7_kernel<<<dim3(4, 4, 128), 256, 0, stream>>>(W0, w3c, b3, x10buf, W2);
    fwht_kernel_t<true><<<NPLANES, 512, 0, stream>>>(W2, v3, T3, W1, W0, klpart + 2 * 262144);
    convt4_kernel<<<dim3(4, 4, 128), 256, 0, stream>>>(W0, w4p, b4, x, out);
    tv_kernel<<<2048, 256, 0, stream>>>(out, tvpart);
    reduce1_kernel<<<49, 256, 0, stream>>>(klpart, tvpart, klred, tvred);
    finalize2_kernel<<<1, 64, 0, stream>>>(klred, tvred, out + 8388608);
}